// Round 4
// baseline (11.641 us; speedup 1.0000x reference)
//
#include <hip/hip_runtime.h>

#define NN 128

typedef __attribute__((ext_vector_type(8))) short short8;
typedef __attribute__((ext_vector_type(4))) float f32x4;

// XOR-swizzled LDS index (units = shorts) for row-major [rows][128] bf16.
// Flips the 16B granule by row&7 -> 16-row column-slice ds_read_b128 hits all
// 32 banks at 2-way max (free). Bits <3 untouched -> 16B alignment preserved.
__device__ __forceinline__ int SWZ(int r, int cs) {
    return (r << 7) + (cs ^ ((r & 7) << 3));
}

__device__ __forceinline__ unsigned asu(float x) { return __float_as_uint(x); }
__device__ __forceinline__ float asf(unsigned u) { return __uint_as_float(u); }

// Fused GAT attention, reg-resident softmax.
// grid = 512: t = bid & 63 (XCD-shared A[t] in L2), i-block = bid >> 6 (16 rows).
// block = 256 (4 waves); LDS ~70 KB -> 2 blocks/CU.
__global__ __launch_bounds__(256, 2) void gat_fused(
    const float* __restrict__ A, const float* __restrict__ W,
    const float* __restrict__ b, float* __restrict__ out)
{
    __shared__ unsigned short Ah_s[NN * NN];   // bf16 hi of A[t,f,j]  (32 KB)
    __shared__ unsigned short Al_s[NN * NN];   // bf16 lo residual     (32 KB)
    __shared__ float w_s[2 * NN];
    __shared__ float part1_s[4 * NN], part2_s[4 * NN];
    __shared__ float s1_s[NN], s2_s[NN];

    const int tid  = threadIdx.x;
    const int lane = tid & 63;
    const int wid  = tid >> 6;
    const int t    = blockIdx.x & 63;
    const int i0   = (blockIdx.x >> 6) << 4;
    const float* At = A + (size_t)t * NN * NN;
    const float b0 = b[0];

    if (tid < 64)
        reinterpret_cast<float4*>(w_s)[tid] = reinterpret_cast<const float4*>(W)[tid];
    __syncthreads();

    // ---- stage A[t] -> (hi,lo) bf16 LDS (truncation split); fused fp32 s1/s2 partials ----
    {
        const float4* A4 = reinterpret_cast<const float4*>(At);
        float p1[4] = {0,0,0,0}, p2[4] = {0,0,0,0};
        #pragma unroll
        for (int it = 0; it < 16; ++it) {
            int e4 = it * 256 + tid;          // float4 index 0..4095
            int f  = e4 >> 5;                 // A row (k of s1/s2)
            int cs = (e4 & 31) << 2;          // column
            float4 v = A4[e4];
            float wf1 = w_s[f], wf2 = w_s[NN + f];
            p1[0] += wf1 * v.x; p1[1] += wf1 * v.y; p1[2] += wf1 * v.z; p1[3] += wf1 * v.w;
            p2[0] += wf2 * v.x; p2[1] += wf2 * v.y; p2[2] += wf2 * v.z; p2[3] += wf2 * v.w;
            unsigned ux = asu(v.x), uy = asu(v.y), uz = asu(v.z), uw = asu(v.w);
            float rx = v.x - asf(ux & 0xffff0000u);
            float ry = v.y - asf(uy & 0xffff0000u);
            float rz = v.z - asf(uz & 0xffff0000u);
            float rw = v.w - asf(uw & 0xffff0000u);
            uint2 hv, lv;
            hv.x = (ux >> 16) | (uy & 0xffff0000u);
            hv.y = (uz >> 16) | (uw & 0xffff0000u);
            lv.x = (asu(rx) >> 16) | (asu(ry) & 0xffff0000u);
            lv.y = (asu(rz) >> 16) | (asu(rw) & 0xffff0000u);
            int idx = SWZ(f, cs);
            *reinterpret_cast<uint2*>(&Ah_s[idx]) = hv;
            *reinterpret_cast<uint2*>(&Al_s[idx]) = lv;
        }
        #pragma unroll
        for (int q = 0; q < 4; ++q) {
            p1[q] += __shfl_xor(p1[q], 32);
            p2[q] += __shfl_xor(p2[q], 32);
        }
        if (lane < 32) {
            float4 v1 = { p1[0], p1[1], p1[2], p1[3] };
            float4 v2 = { p2[0], p2[1], p2[2], p2[3] };
            *reinterpret_cast<float4*>(&part1_s[wid * NN + lane * 4]) = v1;
            *reinterpret_cast<float4*>(&part2_s[wid * NN + lane * 4]) = v2;
        }
    }
    __syncthreads();

    if (tid < NN) {
        s1_s[tid] = part1_s[tid] + part1_s[NN + tid]
                  + part1_s[2 * NN + tid] + part1_s[3 * NN + tid] + b0;
        s2_s[tid] = part2_s[tid] + part2_s[NN + tid]
                  + part2_s[2 * NN + tid] + part2_s[3 * NN + tid];
    }
    __syncthreads();

    // ---- per-wave: B-frags -> regs, in-register softmax -> A-frags, MFMA, store ----
    {
        const int f0 = wid * 32;              // wave's 32 output cols
        const int ar = lane & 15;             // frag row / B frag row
        const int kg = (lane >> 4) << 3;      // k sub-group offset

        // B fragments (Ah, Al), read once, reused across passes.
        short8 bh0[4], bh1[4], bl0[4], bl1[4];
        #pragma unroll
        for (int k = 0; k < 4; ++k) {
            int c = k * 32 + kg;
            bh0[k] = *reinterpret_cast<const short8*>(&Ah_s[SWZ(f0 + ar, c)]);
            bh1[k] = *reinterpret_cast<const short8*>(&Ah_s[SWZ(f0 + 16 + ar, c)]);
            bl0[k] = *reinterpret_cast<const short8*>(&Al_s[SWZ(f0 + ar, c)]);
            bl1[k] = *reinterpret_cast<const short8*>(&Al_s[SWZ(f0 + 16 + ar, c)]);
        }

        // Softmax for row i0+ar over this lane's 32 cols (k*32+kg+e).
        // Row group = lanes {ar, ar+16, ar+32, ar+48} -> shfl_xor 16/32.
        float s1v = s1_s[i0 + ar];
        float ev[32];
        float m = -3.4e38f;
        #pragma unroll
        for (int k = 0; k < 4; ++k) {
            float4 sa = *reinterpret_cast<const float4*>(&s2_s[k * 32 + kg]);
            float4 sb = *reinterpret_cast<const float4*>(&s2_s[k * 32 + kg + 4]);
            float xs[8] = { sa.x, sa.y, sa.z, sa.w, sb.x, sb.y, sb.z, sb.w };
            #pragma unroll
            for (int e = 0; e < 8; ++e) {
                float x = s1v + xs[e];
                x = (x >= 0.f) ? x : 0.2f * x;          // leaky_relu 0.2
                ev[k * 8 + e] = x;
                m = fmaxf(m, x);
            }
        }
        m = fmaxf(m, __shfl_xor(m, 16));
        m = fmaxf(m, __shfl_xor(m, 32));
        float s = 0.f;
        #pragma unroll
        for (int c = 0; c < 32; ++c) { ev[c] = __expf(ev[c] - m); s += ev[c]; }
        s += __shfl_xor(s, 16);
        s += __shfl_xor(s, 32);
        float inv = 1.0f / s;

        // Pack alpha -> hi/lo bf16 A-fragments in registers.
        short8 ah[4], al[4];
        #pragma unroll
        for (int k = 0; k < 4; ++k) {
            union { short8 s8; uint4 u4; } H, L;
            #pragma unroll
            for (int p = 0; p < 4; ++p) {
                float v0 = ev[k * 8 + 2 * p]     * inv;
                float v1 = ev[k * 8 + 2 * p + 1] * inv;
                unsigned u0 = asu(v0), u1 = asu(v1);
                float r0 = v0 - asf(u0 & 0xffff0000u);
                float r1 = v1 - asf(u1 & 0xffff0000u);
                unsigned hw = (u0 >> 16) | (u1 & 0xffff0000u);
                unsigned lw = (asu(r0) >> 16) | (asu(r1) & 0xffff0000u);
                if (p == 0) { H.u4.x = hw; L.u4.x = lw; }
                else if (p == 1) { H.u4.y = hw; L.u4.y = lw; }
                else if (p == 2) { H.u4.z = hw; L.u4.z = lw; }
                else { H.u4.w = hw; L.u4.w = lw; }
            }
            ah[k] = H.s8;
            al[k] = L.s8;
        }

        // PV: 3 passes (ah*Ah + ah*Al + al*Ah), all operands in registers.
        f32x4 acc0 = {0.f,0.f,0.f,0.f}, acc1 = {0.f,0.f,0.f,0.f};
        #pragma unroll
        for (int k = 0; k < 4; ++k) {
            acc0 = __builtin_amdgcn_mfma_f32_16x16x32_bf16(ah[k], bh0[k], acc0, 0, 0, 0);
            acc1 = __builtin_amdgcn_mfma_f32_16x16x32_bf16(ah[k], bh1[k], acc1, 0, 0, 0);
        }
        #pragma unroll
        for (int k = 0; k < 4; ++k) {
            acc0 = __builtin_amdgcn_mfma_f32_16x16x32_bf16(ah[k], bl0[k], acc0, 0, 0, 0);
            acc1 = __builtin_amdgcn_mfma_f32_16x16x32_bf16(ah[k], bl1[k], acc1, 0, 0, 0);
        }
        #pragma unroll
        for (int k = 0; k < 4; ++k) {
            acc0 = __builtin_amdgcn_mfma_f32_16x16x32_bf16(al[k], bh0[k], acc0, 0, 0, 0);
            acc1 = __builtin_amdgcn_mfma_f32_16x16x32_bf16(al[k], bh1[k], acc1, 0, 0, 0);
        }

        // C/D: col = lane&15, row = (lane>>4)*4 + q
        float* outt = out + (size_t)t * NN * NN;
        int orow = i0 + ((lane >> 4) << 2);
        int col  = lane & 15;
        #pragma unroll
        for (int q = 0; q < 4; ++q) {
            outt[(orow + q) * NN + f0 + col]      = acc0[q];
            outt[(orow + q) * NN + f0 + 16 + col] = acc1[q];
        }
    }
}

extern "C" void kernel_launch(void* const* d_in, const int* in_sizes, int n_in,
                              void* d_out, int out_size, void* d_ws, size_t ws_size,
                              hipStream_t stream) {
    const float* A = (const float*)d_in[0];
    const float* W = (const float*)d_in[1];
    const float* b = (const float*)d_in[2];
    float* out = (float*)d_out;
    gat_fused<<<dim3(512), dim3(256), 0, stream>>>(A, W, b, out);
}